// Round 5
// baseline (121.558 us; speedup 1.0000x reference)
//
#include <hip/hip_runtime.h>

// LSHAttention: reference returns ONLY sticker = argsort(buckets) [B,S] int32.
// B=4, S=4096, D=1024, NR=32, 64 buckets.
// k1: block = 1024 thr = 16 waves = one 64-token chunk; wave w = k-slice of 64.
//     lane = (r = lane&31, khalf = lane>>5).
//     R (k-major [1024][32]) -> 32 VGPRs per lane via 32 coalesced loads, ONCE.
//     Q: per token, lane reads its khalf's 32 floats (8x float4, 2 lines/instr,
//     every line consumed once -> clean 64MB stream). 32 FMA (4 partial accs),
//     shfl_xor(32) half-combine, LDS write. Token loop unrolled x2 (qA/qB).
//     Combine: padded buf[16][64][33] -> parallel sum -> xs[32][64] -> argmax.
// k2: offset scan; k3: stable scatter (verified absmax 0, rounds 1-4).

#define B_DIM 4
#define S_LEN 4096
#define D_DIM 1024
#define NR 32
#define NBK 64
#define TM 64
#define NCHUNK (S_LEN / TM)   // 64
#define NW 16                 // waves per block (k-slices)
#define BUFP (NR + 1)         // 33: bank-spread pad

__global__ __launch_bounds__(1024, 4) void k1_buckets(
    const float* __restrict__ Q, const float* __restrict__ R,
    int* __restrict__ buckets, int* __restrict__ hist)
{
    __shared__ float buf[NW * TM * BUFP];   // 132 KB partials [w][tok][r]
    __shared__ float xs[NR * TM];           // 8 KB sums [r][tok]
    __shared__ int cnt[NBK];

    const int t = threadIdx.x;
    const int b = blockIdx.x >> 6;
    const int chunk = blockIdx.x & 63;
    const int w = t >> 6;                  // k-slice (wave-uniform)
    const int lane = t & 63;
    const int r = lane & 31;
    const int half = lane >> 5;

    // ---- R slice -> registers: Rreg[j] = R[b][w*64 + half*32 + j][r] ----
    const float* Rb = R + (size_t)b * D_DIM * NR + (size_t)(w * 64 + half * 32) * NR + r;
    float Rreg[32];
#pragma unroll
    for (int j = 0; j < 32; ++j) Rreg[j] = Rb[j * NR];

    const float* Qb = Q + ((size_t)b * S_LEN + chunk * TM) * D_DIM
                    + w * 64 + half * 32;

    float4 qA[8], qB[8];
#pragma unroll
    for (int i = 0; i < 8; ++i)
        qA[i] = *reinterpret_cast<const float4*>(Qb + 0 * D_DIM + i * 4);

#define COMPUTE(QV, TOK)                                                     \
    {                                                                        \
        float a0 = 0.f, a1 = 0.f, a2 = 0.f, a3 = 0.f;                        \
        _Pragma("unroll")                                                    \
        for (int i = 0; i < 8; ++i) {                                        \
            a0 = fmaf(QV[i].x, Rreg[i * 4 + 0], a0);                         \
            a1 = fmaf(QV[i].y, Rreg[i * 4 + 1], a1);                         \
            a2 = fmaf(QV[i].z, Rreg[i * 4 + 2], a2);                         \
            a3 = fmaf(QV[i].w, Rreg[i * 4 + 3], a3);                         \
        }                                                                    \
        float s = (a0 + a1) + (a2 + a3);                                     \
        s += __shfl_xor(s, 32, 64);                                          \
        buf[(w * TM + (TOK)) * BUFP + r] = s;                                \
    }

    for (int tok = 0; tok < TM; tok += 2) {
#pragma unroll
        for (int i = 0; i < 8; ++i)
            qB[i] = *reinterpret_cast<const float4*>(Qb + (size_t)(tok + 1) * D_DIM + i * 4);
        COMPUTE(qA, tok)
        if (tok + 2 < TM) {
#pragma unroll
            for (int i = 0; i < 8; ++i)
                qA[i] = *reinterpret_cast<const float4*>(Qb + (size_t)(tok + 2) * D_DIM + i * 4);
        }
        COMPUTE(qB, tok + 1)
    }
#undef COMPUTE

    if (t < NBK) cnt[t] = 0;
    __syncthreads();   // buf complete, cnt zeroed

    // ---- parallel combine: 2048 (r,tok) items over 1024 threads ----
#pragma unroll
    for (int it = 0; it < 2; ++it) {
        const int p = t + it * 1024;
        const int rr = p >> 6;
        const int tk = p & 63;
        float s = 0.f;
#pragma unroll
        for (int ww = 0; ww < NW; ++ww)
            s += buf[(ww * TM + tk) * BUFP + rr];
        xs[rr * TM + tk] = s;
    }
    __syncthreads();   // xs ready

    if (t < TM) {
        // argmax(concat[xR,-xR]) with first-occurrence tie-break
        float m1 = xs[0 * TM + t]; int i1 = 0;
        float m2 = m1;             int i2 = 0;
#pragma unroll
        for (int rr = 1; rr < NR; ++rr) {
            const float v = xs[rr * TM + t];
            if (v > m1) { m1 = v; i1 = rr; }
            if (v < m2) { m2 = v; i2 = rr; }
        }
        const int bk = (m1 >= -m2) ? i1 : (NR + i2);
        buckets[(size_t)b * S_LEN + chunk * TM + t] = bk;
        atomicAdd(&cnt[bk], 1);
    }
    __syncthreads();
    if (t < NBK) hist[((size_t)b * NCHUNK + chunk) * NBK + t] = cnt[t];
}

// One block, 256 threads: thread = (batch b = t/64, bucket bk = t%64).
__global__ __launch_bounds__(256) void k2_scan(
    const int* __restrict__ hist, int* __restrict__ chunkOffset)
{
    const int t = threadIdx.x;
    const int b = t >> 6;
    const int bk = t & 63;
    const int lane = t & 63;

    int total = 0;
    for (int c = 0; c < NCHUNK; ++c)
        total += hist[((size_t)b * NCHUNK + c) * NBK + bk];

    int incl = total;
#pragma unroll
    for (int off = 1; off < 64; off <<= 1) {
        int n = __shfl_up(incl, off, 64);
        if (lane >= off) incl += n;
    }
    int run = incl - total;   // exclusive prefix over buckets = bucketStart

    for (int c = 0; c < NCHUNK; ++c) {
        int h = hist[((size_t)b * NCHUNK + c) * NBK + bk];
        chunkOffset[((size_t)b * NCHUNK + c) * NBK + bk] = run;
        run += h;
    }
}

// Stable scatter: wave = 64 consecutive tokens (one chunk).
__global__ __launch_bounds__(256) void k3_scatter(
    const int* __restrict__ buckets, const int* __restrict__ chunkOffset,
    int* __restrict__ out)
{
    const int gid = blockIdx.x * 256 + threadIdx.x;  // 0..16383
    const int b = gid >> 12;
    const int s = gid & (S_LEN - 1);
    const int chunk = s >> 6;
    const int lane = threadIdx.x & 63;

    const int bk = buckets[gid];

    unsigned long long m = ~0ull;
#pragma unroll
    for (int i = 0; i < 6; ++i) {
        unsigned long long bi = __ballot((bk >> i) & 1);
        m &= ((bk >> i) & 1) ? bi : ~bi;
    }
    int rank = __popcll(m & ((1ull << lane) - 1ull));

    int pos = chunkOffset[((size_t)b * NCHUNK + chunk) * NBK + bk] + rank;
    out[(size_t)b * S_LEN + pos] = s;
}

extern "C" void kernel_launch(void* const* d_in, const int* in_sizes, int n_in,
                              void* d_out, int out_size, void* d_ws, size_t ws_size,
                              hipStream_t stream) {
    const float* Q = (const float*)d_in[0];
    // d_in[1] = key, d_in[2] = value: dead code in the reference, never read.
    const float* R = (const float*)d_in[3];

    int* buckets     = (int*)d_ws;                      // 16384 ints
    int* hist        = buckets + B_DIM * S_LEN;         // 16384 ints
    int* chunkOffset = hist + B_DIM * NCHUNK * NBK;     // 16384 ints

    k1_buckets<<<B_DIM * NCHUNK, 1024, 0, stream>>>(Q, R, buckets, hist);
    k2_scan   <<<1,              256,  0, stream>>>(hist, chunkOffset);
    k3_scatter<<<(B_DIM * S_LEN) / 256, 256, 0, stream>>>(buckets, chunkOffset, (int*)d_out);
}

// Round 6
// 81.840 us; speedup vs baseline: 1.4853x; 1.4853x over previous
//
#include <hip/hip_runtime.h>

// LSHAttention: reference returns ONLY sticker = argsort(buckets) [B,S] int32.
// B=4, S=4096, D=1024, NR=32, 64 buckets.
// k1: 1024 blocks = (b:4, chunk32:128, khalf:2), 256 thr, 4 waves.
//     K-tiles of 128: Q tile + R tile staged in LDS (XOR-swizzled, conflict-
//     free), register-prefetch of next tile overlaps compute. Thread owns
//     4 tok x 4 r (acc 16); waves k-split the tile; LDS reduce; wave 0 stores
//     partials P[b][c32][khalf][32tok][32r] (deterministic 2-stage K-split).
// k1c: 256 blocks: sum 2 K-halves -> argmax -> buckets + 64-token-chunk hist.
// k2: offset scan; k3: stable scatter (verified absmax 0, rounds 1-5).

#define B_DIM 4
#define S_LEN 4096
#define D_DIM 1024
#define NRR 32
#define NBK 64
#define TMK 32                 // tokens per k1 block
#define NC32 (S_LEN / TMK)     // 128
#define KQ 2                   // K-split factor
#define KHALF (D_DIM / KQ)     // 512
#define KB 128                 // k per tile
#define NTILE (KHALF / KB)     // 4
#define HCH 64                 // hist/scatter chunk (matches k2/k3)
#define NCHUNK (S_LEN / HCH)   // 64
#define PSLICE (TMK * NRR)     // 1024 floats per (block) partial slice

__global__ __launch_bounds__(256, 4) void k1_gemm(
    const float* __restrict__ Q, const float* __restrict__ R,
    float* __restrict__ P)
{
    // lds[0..4096)   : Qs[32][128]  (swizzled by tok>>2)
    // lds[4096..8192): Rst[32][128] (swizzled by r>>2)
    // lds[0..5120)   : red[4][64][20] (reuse after final barrier)
    __shared__ float lds[8192];

    const int bid = blockIdx.x;
    const int kq  = bid & 1;
    const int c32 = (bid >> 1) & (NC32 - 1);
    const int b   = bid >> 8;
    const int t    = threadIdx.x;
    const int w    = t >> 6;
    const int lane = t & 63;
    const int tq = lane >> 3;   // token-quad 0..7
    const int rq = lane & 7;    // r-quad 0..7

    const float* Qg = Q + ((size_t)b * S_LEN + c32 * TMK) * D_DIM + kq * KHALF;
    const float* Rg = R + (size_t)b * D_DIM * NRR + (size_t)kq * KHALF * NRR;

    float4 qpf[4], rpf[4];
    // prologue: prefetch tile 0 (coalesced 1KB/instr for both streams)
#pragma unroll
    for (int i = 0; i < 4; ++i) {
        const int id = t + 256 * i;
        const int tok = id >> 5, c4 = id & 31;
        qpf[i] = *(const float4*)(Qg + (size_t)tok * D_DIM + c4 * 4);
    }
#pragma unroll
    for (int i = 0; i < 4; ++i) {
        const int id = t + 256 * i;
        const int k = id >> 3, a = id & 7;
        rpf[i] = *(const float4*)(Rg + (size_t)k * NRR + a * 4);
    }

    float4 acc[4];
#pragma unroll
    for (int j = 0; j < 4; ++j) acc[j] = make_float4(0.f, 0.f, 0.f, 0.f);

    for (int tile = 0; tile < NTILE; ++tile) {
        if (tile) __syncthreads();          // prev compute done, LDS free
        // commit staged registers to LDS (swizzled)
#pragma unroll
        for (int i = 0; i < 4; ++i) {
            const int id = t + 256 * i;
            const int tok = id >> 5, c4 = id & 31;
            const int kx = (c4 * 4) ^ ((tok >> 2) << 2);
            *(float4*)&lds[tok * KB + kx] = qpf[i];
        }
#pragma unroll
        for (int i = 0; i < 4; ++i) {
            const int id = t + 256 * i;
            const int k = id >> 3, a = id & 7;
            const int kx = k ^ (a << 2);    // (r>>2)==a for r=a*4+j
            lds[4096 + (a * 4 + 0) * KB + kx] = rpf[i].x;
            lds[4096 + (a * 4 + 1) * KB + kx] = rpf[i].y;
            lds[4096 + (a * 4 + 2) * KB + kx] = rpf[i].z;
            lds[4096 + (a * 4 + 3) * KB + kx] = rpf[i].w;
        }
        __syncthreads();
        // prefetch next tile (in flight during compute)
        if (tile + 1 < NTILE) {
            const int k0 = (tile + 1) * KB;
#pragma unroll
            for (int i = 0; i < 4; ++i) {
                const int id = t + 256 * i;
                const int tok = id >> 5, c4 = id & 31;
                qpf[i] = *(const float4*)(Qg + (size_t)tok * D_DIM + k0 + c4 * 4);
            }
#pragma unroll
            for (int i = 0; i < 4; ++i) {
                const int id = t + 256 * i;
                const int k = id >> 3, a = id & 7;
                rpf[i] = *(const float4*)(Rg + (size_t)(k0 + k) * NRR + a * 4);
            }
        }
        // compute: wave w covers kk in [w*32, w*32+32)
        const int kks = w * 32;
#pragma unroll
        for (int kk4 = 0; kk4 < 32; kk4 += 4) {
            const int kk = kks + kk4;
            const int qx = kk ^ (tq << 2);
            const int rx = kk ^ (rq << 2);
            float4 qv[4], rv[4];
#pragma unroll
            for (int j = 0; j < 4; ++j)
                qv[j] = *(const float4*)&lds[(tq * 4 + j) * KB + qx];
#pragma unroll
            for (int jj = 0; jj < 4; ++jj)
                rv[jj] = *(const float4*)&lds[4096 + (rq * 4 + jj) * KB + rx];
#pragma unroll
            for (int j = 0; j < 4; ++j) {
                acc[j].x = fmaf(qv[j].x, rv[0].x, acc[j].x);
                acc[j].x = fmaf(qv[j].y, rv[0].y, acc[j].x);
                acc[j].x = fmaf(qv[j].z, rv[0].z, acc[j].x);
                acc[j].x = fmaf(qv[j].w, rv[0].w, acc[j].x);
                acc[j].y = fmaf(qv[j].x, rv[1].x, acc[j].y);
                acc[j].y = fmaf(qv[j].y, rv[1].y, acc[j].y);
                acc[j].y = fmaf(qv[j].z, rv[1].z, acc[j].y);
                acc[j].y = fmaf(qv[j].w, rv[1].w, acc[j].y);
                acc[j].z = fmaf(qv[j].x, rv[2].x, acc[j].z);
                acc[j].z = fmaf(qv[j].y, rv[2].y, acc[j].z);
                acc[j].z = fmaf(qv[j].z, rv[2].z, acc[j].z);
                acc[j].z = fmaf(qv[j].w, rv[2].w, acc[j].z);
                acc[j].w = fmaf(qv[j].x, rv[3].x, acc[j].w);
                acc[j].w = fmaf(qv[j].y, rv[3].y, acc[j].w);
                acc[j].w = fmaf(qv[j].z, rv[3].z, acc[j].w);
                acc[j].w = fmaf(qv[j].w, rv[3].w, acc[j].w);
            }
        }
    }

    // cross-wave reduce via LDS (reuse), wave 0 stores the block partial
    __syncthreads();
#pragma unroll
    for (int j = 0; j < 4; ++j)
        *(float4*)&lds[(w * 64 + lane) * 20 + j * 4] = acc[j];
    __syncthreads();
    if (w == 0) {
        float* pt = P + (((size_t)b * NC32 + c32) * KQ + kq) * PSLICE;
#pragma unroll
        for (int j = 0; j < 4; ++j) {
            float4 s = *(float4*)&lds[(0 * 64 + lane) * 20 + j * 4];
#pragma unroll
            for (int ww = 1; ww < 4; ++ww) {
                const float4 v = *(float4*)&lds[(ww * 64 + lane) * 20 + j * 4];
                s.x += v.x; s.y += v.y; s.z += v.z; s.w += v.w;
            }
            *(float4*)&pt[(tq * 4 + j) * NRR + rq * 4] = s;
        }
    }
}

// 256 blocks = (b, 64-token chunk): sum 2 K-halves, argmax, bucket, hist.
__global__ __launch_bounds__(256) void k1c_combine(
    const float* __restrict__ P,
    int* __restrict__ buckets, int* __restrict__ hist)
{
    __shared__ float xs[HCH][NRR + 1];
    __shared__ int cnt[NBK];

    const int bid = blockIdx.x;
    const int b = bid >> 6;
    const int h = bid & 63;
    const int t = threadIdx.x;

#pragma unroll
    for (int i = 0; i < 8; ++i) {
        const int idx = t + 256 * i;           // 0..2047 = 64 tok x 32 r
        const int tok = idx >> 5, r = idx & 31;
        const int c32 = h * 2 + (tok >> 5);
        const int tokin = tok & 31;
        const size_t base = (((size_t)b * NC32 + c32) * KQ) * PSLICE
                          + (size_t)tokin * NRR + r;
        xs[tok][r] = P[base] + P[base + PSLICE];
    }
    if (t < NBK) cnt[t] = 0;
    __syncthreads();

    if (t < HCH) {
        // argmax(concat[xR,-xR]) with first-occurrence tie-break
        float m1 = xs[t][0]; int i1 = 0;
        float m2 = m1;       int i2 = 0;
#pragma unroll
        for (int r = 1; r < NRR; ++r) {
            const float v = xs[t][r];
            if (v > m1) { m1 = v; i1 = r; }
            if (v < m2) { m2 = v; i2 = r; }
        }
        const int bk = (m1 >= -m2) ? i1 : (NRR + i2);
        buckets[(size_t)b * S_LEN + h * HCH + t] = bk;
        atomicAdd(&cnt[bk], 1);
    }
    __syncthreads();
    if (t < NBK) hist[((size_t)b * NCHUNK + h) * NBK + t] = cnt[t];
}

// One block, 256 threads: thread = (batch b = t/64, bucket bk = t%64).
__global__ __launch_bounds__(256) void k2_scan(
    const int* __restrict__ hist, int* __restrict__ chunkOffset)
{
    const int t = threadIdx.x;
    const int b = t >> 6;
    const int bk = t & 63;
    const int lane = t & 63;

    int total = 0;
    for (int c = 0; c < NCHUNK; ++c)
        total += hist[((size_t)b * NCHUNK + c) * NBK + bk];

    int incl = total;
#pragma unroll
    for (int off = 1; off < 64; off <<= 1) {
        int n = __shfl_up(incl, off, 64);
        if (lane >= off) incl += n;
    }
    int run = incl - total;   // exclusive prefix over buckets = bucketStart

    for (int c = 0; c < NCHUNK; ++c) {
        int h = hist[((size_t)b * NCHUNK + c) * NBK + bk];
        chunkOffset[((size_t)b * NCHUNK + c) * NBK + bk] = run;
        run += h;
    }
}

// Stable scatter: wave = 64 consecutive tokens (one chunk).
__global__ __launch_bounds__(256) void k3_scatter(
    const int* __restrict__ buckets, const int* __restrict__ chunkOffset,
    int* __restrict__ out)
{
    const int gid = blockIdx.x * 256 + threadIdx.x;  // 0..16383
    const int b = gid >> 12;
    const int s = gid & (S_LEN - 1);
    const int chunk = s >> 6;
    const int lane = threadIdx.x & 63;

    const int bk = buckets[gid];

    unsigned long long m = ~0ull;
#pragma unroll
    for (int i = 0; i < 6; ++i) {
        unsigned long long bi = __ballot((bk >> i) & 1);
        m &= ((bk >> i) & 1) ? bi : ~bi;
    }
    int rank = __popcll(m & ((1ull << lane) - 1ull));

    int pos = chunkOffset[((size_t)b * NCHUNK + chunk) * NBK + bk] + rank;
    out[(size_t)b * S_LEN + pos] = s;
}

extern "C" void kernel_launch(void* const* d_in, const int* in_sizes, int n_in,
                              void* d_out, int out_size, void* d_ws, size_t ws_size,
                              hipStream_t stream) {
    const float* Q = (const float*)d_in[0];
    // d_in[1] = key, d_in[2] = value: dead code in the reference, never read.
    const float* R = (const float*)d_in[3];

    float* P          = (float*)d_ws;    // 4*128*2*1024 floats = 4 MB
    int* buckets      = (int*)(P + (size_t)B_DIM * NC32 * KQ * PSLICE);
    int* hist         = buckets + B_DIM * S_LEN;
    int* chunkOffset  = hist + B_DIM * NCHUNK * NBK;

    k1_gemm    <<<B_DIM * NC32 * KQ, 256, 0, stream>>>(Q, R, P);
    k1c_combine<<<B_DIM * NCHUNK,    256, 0, stream>>>(P, buckets, hist);
    k2_scan    <<<1,                 256, 0, stream>>>(hist, chunkOffset);
    k3_scatter <<<(B_DIM * S_LEN) / 256, 256, 0, stream>>>(buckets, chunkOffset, (int*)d_out);
}

// Round 7
// 44.878 us; speedup vs baseline: 2.7086x; 1.8236x over previous
//
#include <hip/hip_runtime.h>

// LSHAttention: reference returns ONLY sticker = argsort(buckets) [B,S] int32.
// B=4, S=4096, D=1024, NR=32, 64 buckets.
// k1: grid 512 = (b:4, chunk32:128), 512 thr = 8 waves, FULL K in block.
//     K-tiles of 256: Q tile [32tok][256k] (quad-XOR-swizzled by tok>>3) +
//     R tile [256k][32r] (natural layout) in LDS, single-buffered, staged
//     via transient regs (no long-lived prefetch regs -> no spill).
//     Thread = (w:8 k-slice32, kh:2 k-sub16, tg:4 tokgroup8, rq:8 rquad):
//     acc 8tok x 4r = 32 VGPR; per 4k: 4 rv + 8 qv ds_read_b128, 128 FMA.
//     shfl_xor(32) kh-merge, 8-wave LDS reduce, in-block argmax + hist.
// k2: offset scan (128 chunks); k3: stable scatter (32-token chunk rank).

#define B_DIM 4
#define S_LEN 4096
#define D_DIM 1024
#define NRR 32
#define NBK 64
#define TMK 32                  // tokens per block = hist chunk
#define NC32 (S_LEN / TMK)      // 128 chunks
#define KB 256                  // k per tile (= Q row stride in LDS)
#define NTILE (D_DIM / KB)      // 4

__global__ void __launch_bounds__(512) __attribute__((amdgpu_waves_per_eu(2, 4)))
k1_buckets(const float* __restrict__ Q, const float* __restrict__ R,
           int* __restrict__ buckets, int* __restrict__ hist)
{
    __shared__ float lds[16384];   // [0,8192): Q tile; [8192,16384): R tile / red
    __shared__ int cnt[NBK];

    const int t = threadIdx.x;
    const int b = blockIdx.x >> 7;
    const int c32 = blockIdx.x & (NC32 - 1);

    const int lane = t & 63;
    const int w = t >> 6;              // 8 waves, k-slice of 32 per tile
    const int rq = lane & 7;           // r-quad (4 r)
    const int tg = (lane >> 3) & 3;    // token-group (8 tokens)
    const int kh = lane >> 5;          // k-half of wave's 32
    const int kbase = w * 32 + kh * 16;

    const float* Qg = Q + ((size_t)b * S_LEN + c32 * TMK) * D_DIM;
    const float* Rg = R + (size_t)b * D_DIM * NRR;

    float4 acc[8];
#pragma unroll
    for (int j = 0; j < 8; ++j) acc[j] = make_float4(0.f, 0.f, 0.f, 0.f);

    for (int tile = 0; tile < NTILE; ++tile) {
        if (tile) __syncthreads();     // prev tile's reads done
        // ---- stage Q tile 32x256 (coalesced 1KB/wave; quad-swizzled write) ----
        {
            const float* Qt = Qg + tile * KB;
#pragma unroll
            for (int i = 0; i < 4; ++i) {
                const int f = t + 512 * i;          // float4 id 0..2047
                const int row = f >> 6;             // 0..31 (wave-uniform)
                const int q = f & 63;               // quad within row
                const float4 v = *(const float4*)(Qt + (size_t)row * D_DIM + q * 4);
                *(float4*)&lds[row * KB + ((q ^ (row >> 3)) << 2)] = v;
            }
            const float* Rt = Rg + (size_t)tile * KB * NRR;
#pragma unroll
            for (int i = 0; i < 4; ++i) {
                const int f = t + 512 * i;          // float4 id 0..2047
                const float4 v = *(const float4*)(Rt + f * 4);
                *(float4*)&lds[8192 + f * 4] = v;
            }
        }
        __syncthreads();
        // ---- compute this thread's 16 k ----
#pragma unroll
        for (int kk4 = 0; kk4 < 4; ++kk4) {
            const int k0 = kbase + kk4 * 4;
            const float4 rv0 = *(const float4*)&lds[8192 + (k0 + 0) * NRR + rq * 4];
            const float4 rv1 = *(const float4*)&lds[8192 + (k0 + 1) * NRR + rq * 4];
            const float4 rv2 = *(const float4*)&lds[8192 + (k0 + 2) * NRR + rq * 4];
            const float4 rv3 = *(const float4*)&lds[8192 + (k0 + 3) * NRR + rq * 4];
            const int qq = (k0 >> 2) ^ tg;          // swizzled quad index
#pragma unroll
            for (int j = 0; j < 8; ++j) {
                const int tok = tg * 8 + j;
                const float4 q = *(const float4*)&lds[tok * KB + (qq << 2)];
                acc[j].x = fmaf(q.x, rv0.x, acc[j].x);
                acc[j].y = fmaf(q.x, rv0.y, acc[j].y);
                acc[j].z = fmaf(q.x, rv0.z, acc[j].z);
                acc[j].w = fmaf(q.x, rv0.w, acc[j].w);
                acc[j].x = fmaf(q.y, rv1.x, acc[j].x);
                acc[j].y = fmaf(q.y, rv1.y, acc[j].y);
                acc[j].z = fmaf(q.y, rv1.z, acc[j].z);
                acc[j].w = fmaf(q.y, rv1.w, acc[j].w);
                acc[j].x = fmaf(q.z, rv2.x, acc[j].x);
                acc[j].y = fmaf(q.z, rv2.y, acc[j].y);
                acc[j].z = fmaf(q.z, rv2.z, acc[j].z);
                acc[j].w = fmaf(q.z, rv2.w, acc[j].w);
                acc[j].x = fmaf(q.w, rv3.x, acc[j].x);
                acc[j].y = fmaf(q.w, rv3.y, acc[j].y);
                acc[j].z = fmaf(q.w, rv3.z, acc[j].z);
                acc[j].w = fmaf(q.w, rv3.w, acc[j].w);
            }
        }
    }

    // ---- kh-merge: lane pairs (x, x^32) share (tg, rq) ----
#pragma unroll
    for (int j = 0; j < 8; ++j) {
        acc[j].x += __shfl_xor(acc[j].x, 32, 64);
        acc[j].y += __shfl_xor(acc[j].y, 32, 64);
        acc[j].z += __shfl_xor(acc[j].z, 32, 64);
        acc[j].w += __shfl_xor(acc[j].w, 32, 64);
    }
    if (t < NBK) cnt[t] = 0;
    __syncthreads();                   // all LDS reads of last tile done

    // ---- per-wave partial [32tok][32r] into R region ----
    if (kh == 0) {
        float* red = &lds[8192 + w * (TMK * NRR)];
#pragma unroll
        for (int j = 0; j < 8; ++j)
            *(float4*)&red[(tg * 8 + j) * NRR + rq * 4] = acc[j];
    }
    __syncthreads();

    // ---- combine 8 waves -> xs[tok][33] in Q region ----
#pragma unroll
    for (int it = 0; it < 2; ++it) {
        const int p = t + it * 512;        // 0..1023 = 32 tok x 32 r
        const int tok = p >> 5, r = p & 31;
        float s = 0.f;
#pragma unroll
        for (int ww = 0; ww < 8; ++ww)
            s += lds[8192 + ww * (TMK * NRR) + tok * NRR + r];
        lds[tok * 33 + r] = s;
    }
    __syncthreads();

    if (t < TMK) {
        // argmax(concat[xR,-xR]) with first-occurrence tie-break
        float m1 = lds[t * 33 + 0]; int i1 = 0;
        float m2 = m1;              int i2 = 0;
#pragma unroll
        for (int r = 1; r < NRR; ++r) {
            const float v = lds[t * 33 + r];
            if (v > m1) { m1 = v; i1 = r; }
            if (v < m2) { m2 = v; i2 = r; }
        }
        const int bk = (m1 >= -m2) ? i1 : (NRR + i2);
        buckets[(size_t)b * S_LEN + c32 * TMK + t] = bk;
        atomicAdd(&cnt[bk], 1);
    }
    __syncthreads();
    if (t < NBK) hist[((size_t)b * NC32 + c32) * NBK + t] = cnt[t];
}

// One block, 256 threads: thread = (batch b = t/64, bucket bk = t%64).
__global__ __launch_bounds__(256) void k2_scan(
    const int* __restrict__ hist, int* __restrict__ chunkOffset)
{
    const int t = threadIdx.x;
    const int b = t >> 6;
    const int bk = t & 63;
    const int lane = t & 63;

    int total = 0;
    for (int c = 0; c < NC32; ++c)
        total += hist[((size_t)b * NC32 + c) * NBK + bk];

    int incl = total;
#pragma unroll
    for (int off = 1; off < 64; off <<= 1) {
        int n = __shfl_up(incl, off, 64);
        if (lane >= off) incl += n;
    }
    int run = incl - total;   // exclusive prefix over buckets = bucketStart

    for (int c = 0; c < NC32; ++c) {
        int h = hist[((size_t)b * NC32 + c) * NBK + bk];
        chunkOffset[((size_t)b * NC32 + c) * NBK + bk] = run;
        run += h;
    }
}

// Stable scatter: 32-token chunks; rank via ballot restricted to own 32-lane half.
__global__ __launch_bounds__(256) void k3_scatter(
    const int* __restrict__ buckets, const int* __restrict__ chunkOffset,
    int* __restrict__ out)
{
    const int gid = blockIdx.x * 256 + threadIdx.x;  // 0..16383
    const int b = gid >> 12;
    const int s = gid & (S_LEN - 1);
    const int chunk = s >> 5;                        // 32-token chunk
    const int lane = threadIdx.x & 63;

    const int bk = buckets[gid];

    unsigned long long m = ~0ull;
#pragma unroll
    for (int i = 0; i < 6; ++i) {
        unsigned long long bi = __ballot((bk >> i) & 1);
        m &= ((bk >> i) & 1) ? bi : ~bi;
    }
    const unsigned int m32 = (unsigned int)(m >> (lane & 32));
    const int rank = __popc(m32 & ((1u << (lane & 31)) - 1u));

    const int pos = chunkOffset[((size_t)b * NC32 + chunk) * NBK + bk] + rank;
    out[(size_t)b * S_LEN + pos] = s;
}

extern "C" void kernel_launch(void* const* d_in, const int* in_sizes, int n_in,
                              void* d_out, int out_size, void* d_ws, size_t ws_size,
                              hipStream_t stream) {
    const float* Q = (const float*)d_in[0];
    // d_in[1] = key, d_in[2] = value: dead code in the reference, never read.
    const float* R = (const float*)d_in[3];

    int* buckets     = (int*)d_ws;                      // 16384 ints
    int* hist        = buckets + B_DIM * S_LEN;         // 4*128*64 = 32768 ints
    int* chunkOffset = hist + B_DIM * NC32 * NBK;       // 32768 ints

    k1_buckets<<<B_DIM * NC32, 512, 0, stream>>>(Q, R, buckets, hist);
    k2_scan   <<<1,            256, 0, stream>>>(hist, chunkOffset);
    k3_scatter<<<(B_DIM * S_LEN) / 256, 256, 0, stream>>>(buckets, chunkOffset, (int*)d_out);
}